// Round 18
// baseline (516.476 us; speedup 1.0000x reference)
//
#include <hip/hip_runtime.h>

#define NN 10000
#define NE 640000
#define D  128
#define PAD_SHIFT 7              // 128 slots/node; P(deg>=128 | mean 64) ~ 3e-13/node
#define GEMM_BLOCKS 313          // ceil(NN/32), 32 rows per 1024-thr block
#define HIST_BLOCKS 32
#define EPB (NE / HIST_BLOCKS)   // 20000 edges per hist block
#define HSIZE 10240              // LDS counter slots (>= NN), 40KB

// ---- zero the global range counter --------------------------------------

__global__ __launch_bounds__(256) void zero_kernel(int* __restrict__ p, int n) {
    int i = blockIdx.x * 256 + threadIdx.x;
    if (i < n) p[i] = 0;
}

// ---- fused: gemm1 (1024-thr tiles) + two-level count&scatter -------------
// Hist blocks: LDS histogram (free atomics) -> per-edge local rank in regs;
// ONE global atomicAdd per (block, touched node) reserves a contiguous
// range (~277K atomics vs 640K per-edge); scatter resolves slot in-thread.
// Output: contiguous padded CSR (consumer-optimal, R17-proven).

union UShared {
    float xs[32][D];             // gemm branch: 16 KB
    int   lh[HSIZE];             // hist branch: 40 KB
};

__global__ __launch_bounds__(1024) void fused_build_kernel(const float* __restrict__ X,
                                                           const float* __restrict__ W,
                                                           float* __restrict__ H,
                                                           const int* __restrict__ ei,
                                                           const float* __restrict__ ew,
                                                           int* __restrict__ cnt,
                                                           int2* __restrict__ epack) {
    __shared__ UShared u;
    int bid = blockIdx.x;
    int t   = threadIdx.x;
    if (bid < GEMM_BLOCKS) {
        // ---- gemm: 32 rows/block, 1024 threads (R9-proven pattern)
        int d  = t & 127;
        int rg = t >> 7;                     // 0..7 -> rows rg*4 .. rg*4+3
        int r0 = bid * 32;
        for (int r = rg; r < 32; r += 8) {
            int rr = r0 + r;
            u.xs[r][d] = (rr < NN) ? X[(size_t)rr * D + d] : 0.0f;
        }
        __syncthreads();
        float acc[4] = {0.f, 0.f, 0.f, 0.f};
        for (int k = 0; k < D; k += 4) {
            float w0 = W[(k + 0) * D + d];
            float w1 = W[(k + 1) * D + d];
            float w2 = W[(k + 2) * D + d];
            float w3 = W[(k + 3) * D + d];
#pragma unroll
            for (int r = 0; r < 4; ++r) {
                float4 xv = *reinterpret_cast<const float4*>(&u.xs[rg * 4 + r][k]);
                acc[r] = fmaf(xv.x, w0, acc[r]);
                acc[r] = fmaf(xv.y, w1, acc[r]);
                acc[r] = fmaf(xv.z, w2, acc[r]);
                acc[r] = fmaf(xv.w, w3, acc[r]);
            }
        }
#pragma unroll
        for (int r = 0; r < 4; ++r) {
            int rr = r0 + rg * 4 + r;
            if (rr < NN) H[(size_t)rr * D + d] = acc[r];
        }
    } else {
        // ---- two-level count & scatter over EPB edges
        int bh = bid - GEMM_BLOCKS;
        int e0 = bh * EPB;
        for (int i = t; i < HSIZE; i += 1024) u.lh[i] = 0;
        __syncthreads();
        // level 1: LDS histogram, remember local rank (u8, packed 4/int)
        unsigned lrp[5] = {0u, 0u, 0u, 0u, 0u};   // 20 ranks max (EPB/1024=19.5)
        for (int j = t, k = 0; j < EPB; j += 1024, ++k) {
            int c  = ei[NE + e0 + j];
            int lr = atomicAdd(&u.lh[c], 1);      // LDS atomic: free
            lrp[k >> 2] |= (unsigned)(lr & 255) << ((k & 3) * 8);
        }
        __syncthreads();
        // level 2: one global range-reserve per touched node
        for (int i = t; i < NN; i += 1024) {
            int hcnt = u.lh[i];
            if (hcnt > 0) u.lh[i] = atomicAdd(&cnt[i], hcnt);   // lh := base
        }
        __syncthreads();
        // scatter: slot = base + local rank (no atomics)
        for (int j = t, k = 0; j < EPB; j += 1024, ++k) {
            int e  = e0 + j;
            int c  = ei[NE + e];
            int lr = (int)((lrp[k >> 2] >> ((k & 3) * 8)) & 255u);
            int slot = u.lh[c] + lr;
            if (slot < (1 << PAD_SHIFT)) {        // overflow guard (P ~ 1e-13)
                int2 v;
                v.x = ei[e];
                v.y = __float_as_int(ew[e]);
                epack[((size_t)c << PAD_SHIFT) + slot] = v;
            }
        }
    }
}

// ---- deg -> dinv from contiguous padded CSR, wave per node --------------

__global__ __launch_bounds__(256) void degdinv_kernel(const int* __restrict__ cnt,
                                                      const int2* __restrict__ epack,
                                                      float* __restrict__ dinv) {
    int node = blockIdx.x * 4 + (threadIdx.x >> 6);
    if (node >= NN) return;
    int lane = threadIdx.x & 63;
    int m = min(cnt[node], 1 << PAD_SHIFT);
    const int2* eb = epack + ((size_t)node << PAD_SHIFT);
    float s = 0.0f;
    for (int j = lane; j < m; j += 64) s += __int_as_float(eb[j].y);
#pragma unroll
    for (int off = 32; off; off >>= 1) s += __shfl_down(s, off);
    if (lane == 0) dinv[node] = rsqrtf(s + 1.0f);      // +1 = self loop
}

// ---- plain gemm (layer 2): 32 rows/block, 256 threads -------------------

__global__ __launch_bounds__(256) void gemm_kernel(const float* __restrict__ X,
                                                   const float* __restrict__ W,
                                                   float* __restrict__ H) {
    __shared__ float xs[32][D];
    int t  = threadIdx.x;
    int d  = t & 127;
    int rh = t >> 7;
    int r0 = blockIdx.x * 32;
#pragma unroll
    for (int r = 0; r < 16; ++r) {
        int rr = r0 + rh * 16 + r;
        xs[rh * 16 + r][d] = (rr < NN) ? X[(size_t)rr * D + d] : 0.0f;
    }
    __syncthreads();
    float acc[16];
#pragma unroll
    for (int r = 0; r < 16; ++r) acc[r] = 0.0f;
    for (int k = 0; k < D; k += 4) {
        float w0 = W[(k + 0) * D + d];
        float w1 = W[(k + 1) * D + d];
        float w2 = W[(k + 2) * D + d];
        float w3 = W[(k + 3) * D + d];
#pragma unroll
        for (int r = 0; r < 16; ++r) {
            float4 xv = *reinterpret_cast<const float4*>(&xs[rh * 16 + r][k]);
            acc[r] = fmaf(xv.x, w0, acc[r]);
            acc[r] = fmaf(xv.y, w1, acc[r]);
            acc[r] = fmaf(xv.z, w2, acc[r]);
            acc[r] = fmaf(xv.w, w3, acc[r]);
        }
    }
#pragma unroll
    for (int r = 0; r < 16; ++r) {
        int rr = r0 + rh * 16 + r;
        if (rr < NN) H[(size_t)rr * D + d] = acc[r];
    }
}

// ---- aggregate: half-feature per block, XCD-parity mapped (R12/R17) -----
// Block i -> (node c, half hh), i = (c/4)*8 + (c%4)*2 + hh: on round-robin
// blockIdx%8 -> XCD dispatch, even XCDs gather only H[:,0:64] (2.56MB),
// odd XCDs H[:,64:128] -> per-XCD gather set fits the 4MB L2.

__global__ __launch_bounds__(64) void agg_half_kernel(const float* __restrict__ H,
                                                      const int* __restrict__ cnt,
                                                      const int2* __restrict__ epack,
                                                      const float* __restrict__ dinv,
                                                      const float* __restrict__ bias,
                                                      float* __restrict__ out) {
    __shared__ int   s_src[128];
    __shared__ float s_n[128];
    int i    = blockIdx.x;
    int slot = i & 7;
    int hh   = slot & 1;
    int c    = (i >> 3) * 4 + (slot >> 1);
    int t    = threadIdx.x;
    int d    = (hh << 6) | t;                 // feature index
    int m    = min(cnt[c], 1 << PAD_SHIFT);
    const int2* eb = epack + ((size_t)c << PAD_SHIFT);
    float di = dinv[c];
    for (int j = t; j < m; j += 64) {
        int2 v = eb[j];
        s_src[j] = v.x;
        s_n[j]   = dinv[v.x] * __int_as_float(v.y);
    }
    __syncthreads();
    float acc = di * H[(size_t)c * D + d];    // self-loop (x di in epilogue)
    int jj = 0;
    for (; jj + 8 <= m; jj += 8) {
#pragma unroll
        for (int k = 0; k < 8; ++k)
            acc = fmaf(s_n[jj + k], H[(size_t)s_src[jj + k] * D + d], acc);
    }
    for (; jj < m; ++jj)
        acc = fmaf(s_n[jj], H[(size_t)s_src[jj] * D + d], acc);
    out[(size_t)c * D + d] = fmaxf(fmaf(di, acc, bias[d]), 0.0f);
}

// ---- launch -------------------------------------------------------------

extern "C" void kernel_launch(void* const* d_in, const int* in_sizes, int n_in,
                              void* d_out, int out_size, void* d_ws, size_t ws_size,
                              hipStream_t stream) {
    const float* x  = (const float*)d_in[0];
    const int*   ei = (const int*)  d_in[1];   // [2, NE]
    const float* ew = (const float*)d_in[2];
    const float* W1 = (const float*)d_in[3];
    const float* b1 = (const float*)d_in[4];
    const float* W2 = (const float*)d_in[5];
    const float* b2 = (const float*)d_in[6];
    float* out = (float*)d_out;

    char* ws = (char*)d_ws;
    size_t off = 0;
    auto alloc = [&](size_t bytes) {
        void* p = ws + off;
        off = (off + bytes + 255) & ~(size_t)255;
        return p;
    };
    int*   cnt   = (int*)  alloc(NN * 4);
    float* dinv  = (float*)alloc(NN * 4);
    int2*  epack = (int2*) alloc(((size_t)NN << PAD_SHIFT) * 8);
    float* h     = (float*)alloc((size_t)NN * D * 4);
    float* g     = (float*)alloc((size_t)NN * D * 4);

    zero_kernel<<<(NN + 255) / 256, 256, 0, stream>>>(cnt, NN);
    fused_build_kernel<<<GEMM_BLOCKS + HIST_BLOCKS, 1024, 0, stream>>>(
        x, W1, h, ei, ew, cnt, epack);
    degdinv_kernel<<<(NN + 3) / 4, 256, 0, stream>>>(cnt, epack, dinv);

    agg_half_kernel<<<NN * 2, 64, 0, stream>>>(h, cnt, epack, dinv, b1, g);
    gemm_kernel    <<<(NN + 31) / 32, 256, 0, stream>>>(g, W2, h);
    agg_half_kernel<<<NN * 2, 64, 0, stream>>>(h, cnt, epack, dinv, b2, out);
}

// Round 19
// 131.791 us; speedup vs baseline: 3.9189x; 3.9189x over previous
//
#include <hip/hip_runtime.h>

#define NN 10000
#define NE 640000
#define D  128
#define PAD_SHIFT 7              // 128 slots/node; deg<128 guaranteed (mean 64, 7.4 sigma)
#define GEMM_BLOCKS ((NN + 31) / 32)
#define CSTRIDE 10240            // per-XCD counter replica stride

// physical XCD id of the wave (0..7 on MI355X). Uniform within a workgroup.
__device__ __forceinline__ int xcc_id() {
    unsigned x;
    asm volatile("s_getreg_b32 %0, hwreg(HW_REG_XCC_ID)" : "=s"(x));
    return (int)(x & 7);
}

// ---- zero the per-XCD counter replicas ----------------------------------

__global__ __launch_bounds__(256) void zero_kernel(int* __restrict__ p, int n) {
    int i = blockIdx.x * 256 + threadIdx.x;
    if (i < n) p[i] = 0;
}

// ---- fused: gemm1 (blocks [0,GEMM_BLOCKS)) + count_rank (rest) ----------

__global__ __launch_bounds__(256) void fused_gemm_count_kernel(const float* __restrict__ X,
                                                               const float* __restrict__ W,
                                                               float* __restrict__ H,
                                                               const int* __restrict__ ei,
                                                               int* __restrict__ cnt8,
                                                               int* __restrict__ rank) {
    int bid = blockIdx.x;
    if (bid < GEMM_BLOCKS) {
        __shared__ float xs[32][D];
        int t  = threadIdx.x;
        int d  = t & 127;
        int rh = t >> 7;
        int r0 = bid * 32;
#pragma unroll
        for (int r = 0; r < 16; ++r) {
            int rr = r0 + rh * 16 + r;
            xs[rh * 16 + r][d] = (rr < NN) ? X[(size_t)rr * D + d] : 0.0f;
        }
        __syncthreads();
        float acc[16];
#pragma unroll
        for (int r = 0; r < 16; ++r) acc[r] = 0.0f;
        for (int k = 0; k < D; k += 4) {
            float w0 = W[(k + 0) * D + d];
            float w1 = W[(k + 1) * D + d];
            float w2 = W[(k + 2) * D + d];
            float w3 = W[(k + 3) * D + d];
#pragma unroll
            for (int r = 0; r < 16; ++r) {
                float4 xv = *reinterpret_cast<const float4*>(&xs[rh * 16 + r][k]);
                acc[r] = fmaf(xv.x, w0, acc[r]);
                acc[r] = fmaf(xv.y, w1, acc[r]);
                acc[r] = fmaf(xv.z, w2, acc[r]);
                acc[r] = fmaf(xv.w, w3, acc[r]);
            }
        }
#pragma unroll
        for (int r = 0; r < 16; ++r) {
            int rr = r0 + rh * 16 + r;
            if (rr < NN) H[(size_t)rr * D + d] = acc[r];
        }
    } else {
        int e = (bid - GEMM_BLOCKS) * 256 + threadIdx.x;
        if (e < NE) {
            int c = ei[NE + e];
            int x = xcc_id();
            int lr = atomicAdd(&cnt8[x * CSTRIDE + c], 1);
            rank[e] = (x << 16) | lr;
        }
    }
}

// ---- per-node 8-way prefix: cnt8 -> base8 (in place) + total cnt --------

__global__ __launch_bounds__(256) void base_kernel(int* __restrict__ cnt8,
                                                   int* __restrict__ cnt) {
    int n = blockIdx.x * 256 + threadIdx.x;
    if (n >= NN) return;
    int b = 0;
#pragma unroll
    for (int x = 0; x < 8; ++x) {
        int t = cnt8[x * CSTRIDE + n];
        cnt8[x * CSTRIDE + n] = b;     // exclusive prefix = this XCD's base
        b += t;
    }
    cnt[n] = b;
}

// ---- atomic-free scatter into padded CSR --------------------------------

__global__ __launch_bounds__(256) void scatter_kernel(const int* __restrict__ ei,
                                                      const float* __restrict__ ew,
                                                      const int* __restrict__ rank,
                                                      const int* __restrict__ base8,
                                                      int2* __restrict__ epack) {
    int e = blockIdx.x * 256 + threadIdx.x;
    if (e < NE) {
        int c  = ei[NE + e];
        int rk = rank[e];
        int x  = rk >> 16;
        int lr = rk & 0xFFFF;
        int2 v;
        v.x = ei[e];
        v.y = __float_as_int(ew[e]);
        epack[((size_t)c << PAD_SHIFT) + base8[x * CSTRIDE + c] + lr] = v;
    }
}

// ---- deg -> dinv from padded CSR, wave per node -------------------------

__global__ __launch_bounds__(256) void degdinv_kernel(const int* __restrict__ cnt,
                                                      const int2* __restrict__ epack,
                                                      float* __restrict__ dinv) {
    int node = blockIdx.x * 4 + (threadIdx.x >> 6);
    if (node >= NN) return;
    int lane = threadIdx.x & 63;
    int m = cnt[node];
    const int2* base = epack + ((size_t)node << PAD_SHIFT);
    float s = 0.0f;
    for (int j = lane; j < m; j += 64) s += __int_as_float(base[j].y);
#pragma unroll
    for (int off = 32; off; off >>= 1) s += __shfl_down(s, off);
    if (lane == 0) dinv[node] = rsqrtf(s + 1.0f);      // +1 = self loop
}

// ---- plain gemm (layer 2): 32 rows/block, 256 threads -------------------

__global__ __launch_bounds__(256) void gemm_kernel(const float* __restrict__ X,
                                                   const float* __restrict__ W,
                                                   float* __restrict__ H) {
    __shared__ float xs[32][D];
    int t  = threadIdx.x;
    int d  = t & 127;
    int rh = t >> 7;
    int r0 = blockIdx.x * 32;
#pragma unroll
    for (int r = 0; r < 16; ++r) {
        int rr = r0 + rh * 16 + r;
        xs[rh * 16 + r][d] = (rr < NN) ? X[(size_t)rr * D + d] : 0.0f;
    }
    __syncthreads();
    float acc[16];
#pragma unroll
    for (int r = 0; r < 16; ++r) acc[r] = 0.0f;
    for (int k = 0; k < D; k += 4) {
        float w0 = W[(k + 0) * D + d];
        float w1 = W[(k + 1) * D + d];
        float w2 = W[(k + 2) * D + d];
        float w3 = W[(k + 3) * D + d];
#pragma unroll
        for (int r = 0; r < 16; ++r) {
            float4 xv = *reinterpret_cast<const float4*>(&xs[rh * 16 + r][k]);
            acc[r] = fmaf(xv.x, w0, acc[r]);
            acc[r] = fmaf(xv.y, w1, acc[r]);
            acc[r] = fmaf(xv.z, w2, acc[r]);
            acc[r] = fmaf(xv.w, w3, acc[r]);
        }
    }
#pragma unroll
    for (int r = 0; r < 16; ++r) {
        int rr = r0 + rh * 16 + r;
        if (rr < NN) H[(size_t)rr * D + d] = acc[r];
    }
}

// ---- aggregate: half-feature per block, XCD-parity mapped ---------------
// Block i -> (node c, half hh) with i = (c/4)*8 + (c%4)*2 + hh, so on the
// round-robin blockIdx%8 -> XCD dispatch, even XCDs only gather H[:,0:64]
// (2.56 MB) and odd XCDs H[:,64:128] -> per-XCD gather set fits 4MB L2.
// One wave (64 threads) per block; LDS-staged edge meta.

__global__ __launch_bounds__(64) void agg_half_kernel(const float* __restrict__ H,
                                                      const int* __restrict__ cnt,
                                                      const int2* __restrict__ epack,
                                                      const float* __restrict__ dinv,
                                                      const float* __restrict__ bias,
                                                      float* __restrict__ out) {
    __shared__ int   s_src[128];
    __shared__ float s_n[128];
    int i    = blockIdx.x;
    int slot = i & 7;
    int hh   = slot & 1;
    int c    = (i >> 3) * 4 + (slot >> 1);
    int t    = threadIdx.x;
    int d    = (hh << 6) | t;                 // feature index
    int m    = cnt[c];
    const int2* eb = epack + ((size_t)c << PAD_SHIFT);
    float di = dinv[c];
    for (int j = t; j < m; j += 64) {
        int2 v = eb[j];
        s_src[j] = v.x;
        s_n[j]   = dinv[v.x] * __int_as_float(v.y);
    }
    __syncthreads();
    float acc = di * H[(size_t)c * D + d];    // self-loop (x di in epilogue)
    int jj = 0;
    for (; jj + 8 <= m; jj += 8) {
#pragma unroll
        for (int k = 0; k < 8; ++k)
            acc = fmaf(s_n[jj + k], H[(size_t)s_src[jj + k] * D + d], acc);
    }
    for (; jj < m; ++jj)
        acc = fmaf(s_n[jj], H[(size_t)s_src[jj] * D + d], acc);
    out[(size_t)c * D + d] = fmaxf(fmaf(di, acc, bias[d]), 0.0f);
}

// ---- launch -------------------------------------------------------------

extern "C" void kernel_launch(void* const* d_in, const int* in_sizes, int n_in,
                              void* d_out, int out_size, void* d_ws, size_t ws_size,
                              hipStream_t stream) {
    const float* x  = (const float*)d_in[0];
    const int*   ei = (const int*)  d_in[1];   // [2, NE]
    const float* ew = (const float*)d_in[2];
    const float* W1 = (const float*)d_in[3];
    const float* b1 = (const float*)d_in[4];
    const float* W2 = (const float*)d_in[5];
    const float* b2 = (const float*)d_in[6];
    float* out = (float*)d_out;

    char* ws = (char*)d_ws;
    size_t off = 0;
    auto alloc = [&](size_t bytes) {
        void* p = ws + off;
        off = (off + bytes + 255) & ~(size_t)255;
        return p;
    };
    int*   cnt8  = (int*)  alloc(8 * CSTRIDE * 4);
    int*   cnt   = (int*)  alloc(NN * 4);
    float* dinv  = (float*)alloc(NN * 4);
    int*   rank  = (int*)  alloc((size_t)NE * 4);
    int2*  epack = (int2*) alloc(((size_t)NN << PAD_SHIFT) * 8);
    float* h     = (float*)alloc((size_t)NN * D * 4);
    float* g     = (float*)alloc((size_t)NN * D * 4);

    zero_kernel<<<(8 * CSTRIDE + 255) / 256, 256, 0, stream>>>(cnt8, 8 * CSTRIDE);
    fused_gemm_count_kernel<<<GEMM_BLOCKS + (NE + 255) / 256, 256, 0, stream>>>(
        x, W1, h, ei, cnt8, rank);
    base_kernel   <<<(NN + 255) / 256, 256, 0, stream>>>(cnt8, cnt);
    scatter_kernel<<<(NE + 255) / 256, 256, 0, stream>>>(ei, ew, rank, cnt8, epack);
    degdinv_kernel<<<(NN + 3) / 4, 256, 0, stream>>>(cnt, epack, dinv);

    agg_half_kernel<<<NN * 2, 64, 0, stream>>>(h, cnt, epack, dinv, b1, g);
    gemm_kernel    <<<(NN + 31) / 32, 256, 0, stream>>>(g, W2, h);
    agg_half_kernel<<<NN * 2, 64, 0, stream>>>(h, cnt, epack, dinv, b2, out);
}